// Round 1
// baseline (149.450 us; speedup 1.0000x reference)
//
#include <hip/hip_runtime.h>

// MoE block: B=128,K=32 -> N=4096 tokens, D=1024, H=256, E=32, top-1 routing.
// out[tok] = relu(relu(x[tok] @ W1[e] + b1[e]) @ W2[e] + b2[e]), e = argmax(x@rw.T+rb)

#define N_TOK 4096
#define DDIM  1024
#define HDIM  256
#define NEXP  32

typedef __attribute__((ext_vector_type(8))) short bf16x8;   // 8 bf16 in 4 VGPRs
typedef __attribute__((ext_vector_type(4))) float f32x4;

__device__ __forceinline__ unsigned short f2bf(float f) {   // RNE f32->bf16
  union { float f; unsigned u; } v; v.f = f;
  unsigned r = v.u + 0x7FFFu + ((v.u >> 16) & 1u);
  return (unsigned short)(r >> 16);
}
__device__ __forceinline__ float bf2f(unsigned short h) {
  union { unsigned u; float f; } v; v.u = ((unsigned)h) << 16;
  return v.f;
}

// ---------------- small prep kernels ----------------

__global__ __launch_bounds__(64) void init_counts_kernel(int* __restrict__ counts) {
  if (threadIdx.x < NEXP) counts[threadIdx.x] = 0;
}

// router_w [E][D] f32 -> hi/lo bf16 pair (for fp32-accurate split MFMA router)
__global__ __launch_bounds__(256) void rw_cvt_kernel(const float* __restrict__ rw,
    unsigned short* __restrict__ rwhi, unsigned short* __restrict__ rwlo) {
  int i = blockIdx.x * 256 + threadIdx.x;   // 32*1024 elements, grid=128
  float w = rw[i];
  unsigned short h = f2bf(w);
  rwhi[i] = h;
  rwlo[i] = f2bf(w - bf2f(h));
}

// transpose + cvt: src [E][R][C] f32 -> dst [E][C][R] bf16 (MFMA B wants k-contiguous)
__global__ __launch_bounds__(256) void transpose_cvt_kernel(const float* __restrict__ src,
    unsigned short* __restrict__ dst, int R, int C) {
  __shared__ float tile[64][65];            // +1 pad: conflict-free transposed read
  int e = blockIdx.z;
  int r0 = blockIdx.x * 64, c0 = blockIdx.y * 64;
  const float* s = src + (size_t)e * R * C;
  unsigned short* d = dst + (size_t)e * R * C;
  int t = threadIdx.x;
  int cl = t & 63, rl = t >> 6;             // 64 lanes contiguous in C: coalesced
#pragma unroll
  for (int i = 0; i < 16; i++) {
    int r = i * 4 + rl;
    tile[r][cl] = s[(size_t)(r0 + r) * C + (c0 + cl)];
  }
  __syncthreads();
#pragma unroll
  for (int i = 0; i < 16; i++) {
    int c = i * 4 + rl;
    d[(size_t)(c0 + c) * R + (r0 + cl)] = f2bf(tile[cl][c]);  // banks (cl+c)%32: clean
  }
}

// ---------------- router: fp32-accurate logits via 4-term bf16 split MFMA ----------------
// 1 wave / 16 tokens. Also writes xb (bf16 x) as a side product.
// A frag: row=lane&15, k=(lane>>4)*8+i ; B frag: col=lane&15, same k.
// C/D: col=lane&15, row=(lane>>4)*4+reg  [verified layout]
__global__ __launch_bounds__(64) void router_kernel(
    const float* __restrict__ x, const unsigned short* __restrict__ rwhi,
    const unsigned short* __restrict__ rwlo, const float* __restrict__ rb,
    unsigned short* __restrict__ xb, int* __restrict__ routed, int* __restrict__ counts) {
  int b = blockIdx.x;                 // token tile of 16
  int l = threadIdx.x;
  int m = l & 15, kb = l >> 4;
  int tok = b * 16 + m;
  const float* xrow = x + (size_t)tok * DDIM + kb * 8;
  unsigned short* xbrow = xb + (size_t)tok * DDIM + kb * 8;
  const unsigned short* w0hi = rwhi + (size_t)m * DDIM + kb * 8;
  const unsigned short* w0lo = rwlo + (size_t)m * DDIM + kb * 8;
  const unsigned short* w1hi = rwhi + (size_t)(16 + m) * DDIM + kb * 8;
  const unsigned short* w1lo = rwlo + (size_t)(16 + m) * DDIM + kb * 8;
  f32x4 acc0 = {0.f,0.f,0.f,0.f}, acc1 = {0.f,0.f,0.f,0.f};
  for (int k0 = 0; k0 < DDIM; k0 += 32) {
    float4 xa = *(const float4*)(xrow + k0);
    float4 xc = *(const float4*)(xrow + k0 + 4);
    float xv[8] = {xa.x, xa.y, xa.z, xa.w, xc.x, xc.y, xc.z, xc.w};
    bf16x8 xhi, xlo;
#pragma unroll
    for (int i = 0; i < 8; i++) {
      unsigned short h = f2bf(xv[i]);
      xhi[i] = (short)h;
      xlo[i] = (short)f2bf(xv[i] - bf2f(h));
    }
    *(bf16x8*)(xbrow + k0) = xhi;     // xb written exactly once per (tok,k)
    bf16x8 wh0 = *(const bf16x8*)(w0hi + k0);
    bf16x8 wl0 = *(const bf16x8*)(w0lo + k0);
    bf16x8 wh1 = *(const bf16x8*)(w1hi + k0);
    bf16x8 wl1 = *(const bf16x8*)(w1lo + k0);
    acc0 = __builtin_amdgcn_mfma_f32_16x16x32_bf16(xhi, wh0, acc0, 0, 0, 0);
    acc0 = __builtin_amdgcn_mfma_f32_16x16x32_bf16(xlo, wh0, acc0, 0, 0, 0);
    acc0 = __builtin_amdgcn_mfma_f32_16x16x32_bf16(xhi, wl0, acc0, 0, 0, 0);
    acc0 = __builtin_amdgcn_mfma_f32_16x16x32_bf16(xlo, wl0, acc0, 0, 0, 0);
    acc1 = __builtin_amdgcn_mfma_f32_16x16x32_bf16(xhi, wh1, acc1, 0, 0, 0);
    acc1 = __builtin_amdgcn_mfma_f32_16x16x32_bf16(xlo, wh1, acc1, 0, 0, 0);
    acc1 = __builtin_amdgcn_mfma_f32_16x16x32_bf16(xhi, wl1, acc1, 0, 0, 0);
    acc1 = __builtin_amdgcn_mfma_f32_16x16x32_bf16(xlo, wl1, acc1, 0, 0, 0);
  }
  float rb0 = rb[m], rb1 = rb[16 + m];
#pragma unroll
  for (int r = 0; r < 4; r++) {       // token row = kb*4+r; its 32 logits live in 16 lanes
    float v0 = acc0[r] + rb0;
    float v1 = acc1[r] + rb1;
    float val = v0; int idx = m;
    if (v1 > v0) { val = v1; idx = 16 + m; }   // ties -> smaller e (np.argmax)
#pragma unroll
    for (int s = 1; s < 16; s <<= 1) {
      float ov = __shfl_xor(val, s);
      int oi = __shfl_xor(idx, s);
      if (ov > val || (ov == val && oi < idx)) { val = ov; idx = oi; }
    }
    if (m == 0) {
      routed[b * 16 + kb * 4 + r] = idx;
      atomicAdd(&counts[idx], 1);
    }
  }
}

__global__ __launch_bounds__(64) void scan_kernel(const int* __restrict__ counts,
    int* __restrict__ offsets, int* __restrict__ cursors) {
  if (threadIdx.x == 0) {
    int acc = 0;
    for (int e = 0; e < NEXP; e++) { offsets[e] = acc; cursors[e] = acc; acc += counts[e]; }
    offsets[NEXP] = acc;
  }
}

__global__ __launch_bounds__(256) void scatter_kernel(const int* __restrict__ routed,
    int* __restrict__ cursors, int* __restrict__ order) {
  int n = blockIdx.x * 256 + threadIdx.x;
  if (n < N_TOK) {
    int e = routed[n];
    int pos = atomicAdd(&cursors[e], 1);   // intra-expert order arbitrary: output invariant
    order[pos] = n;
  }
}

// ---------------- grouped expert GEMMs ----------------
// L1: h[tok][0:256] = relu(xb[tok] @ W1[e] + b1[e]),  K=1024
// block: 512 thr = 8 waves; 32-token tile x 256 cols; wave = 16 rows x 64 cols (4 MFMA tiles)
__global__ __launch_bounds__(512) void expert_l1_kernel(
    const unsigned short* __restrict__ xb, const unsigned short* __restrict__ w1t,
    const float* __restrict__ b1, const int* __restrict__ offsets,
    const int* __restrict__ order, unsigned short* __restrict__ hb) {
  int e = blockIdx.x;
  int beg = offsets[e], end = offsets[e + 1];
  int ne = end - beg;
  if (ne <= 0) return;
  int w = threadIdx.x >> 6, l = threadIdx.x & 63;
  int rg = w >> 2, cg = w & 3;
  int m = l & 15, kb = l >> 4;
  const unsigned short* wbase = w1t + (size_t)e * HDIM * DDIM;
  int ntiles = (ne + 31) >> 5;
  for (int tile = blockIdx.y; tile < ntiles; tile += gridDim.y) {
    int ts = beg + tile * 32;
    int nrow = end - ts; if (nrow > 32) nrow = 32;
    int arow = rg * 16 + m;
    int tokA = order[ts + (arow < nrow ? arow : nrow - 1)];  // clamp: masked at store
    const unsigned short* aptr = xb + (size_t)tokA * DDIM + kb * 8;
    f32x4 acc[4];
#pragma unroll
    for (int j = 0; j < 4; j++) acc[j] = (f32x4){0.f,0.f,0.f,0.f};
    for (int k0 = 0; k0 < DDIM; k0 += 32) {
      bf16x8 av = *(const bf16x8*)(aptr + k0);
#pragma unroll
      for (int j = 0; j < 4; j++) {
        int col = cg * 64 + j * 16 + m;
        bf16x8 bv = *(const bf16x8*)(wbase + (size_t)col * DDIM + k0 + kb * 8);
        acc[j] = __builtin_amdgcn_mfma_f32_16x16x32_bf16(av, bv, acc[j], 0, 0, 0);
      }
    }
    float bias[4];
#pragma unroll
    for (int j = 0; j < 4; j++) bias[j] = b1[e * HDIM + cg * 64 + j * 16 + m];
#pragma unroll
    for (int r = 0; r < 4; r++) {
      int crow = rg * 16 + kb * 4 + r;
      if (crow < nrow) {
        int tok = order[ts + crow];
#pragma unroll
        for (int j = 0; j < 4; j++) {
          float v = acc[j][r] + bias[j];
          v = v > 0.f ? v : 0.f;
          hb[(size_t)tok * HDIM + cg * 64 + j * 16 + m] = f2bf(v);
        }
      }
    }
  }
}

// L2: out[tok][dq*256 : +256] = relu(hb[tok] @ W2[e] + b2[e]),  K=256
__global__ __launch_bounds__(512) void expert_l2_kernel(
    const unsigned short* __restrict__ hb, const unsigned short* __restrict__ w2t,
    const float* __restrict__ b2, const int* __restrict__ offsets,
    const int* __restrict__ order, float* __restrict__ out) {
  int e = blockIdx.x;
  int beg = offsets[e], end = offsets[e + 1];
  int ne = end - beg;
  if (ne <= 0) return;
  int w = threadIdx.x >> 6, l = threadIdx.x & 63;
  int rg = w >> 2, cg = w & 3;
  int m = l & 15, kb = l >> 4;
  int dq = blockIdx.z;                 // D quarter: 256 cols
  const unsigned short* wbase = w2t + (size_t)e * DDIM * HDIM + (size_t)dq * 256 * HDIM;
  int ntiles = (ne + 31) >> 5;
  for (int tile = blockIdx.y; tile < ntiles; tile += gridDim.y) {
    int ts = beg + tile * 32;
    int nrow = end - ts; if (nrow > 32) nrow = 32;
    int arow = rg * 16 + m;
    int tokA = order[ts + (arow < nrow ? arow : nrow - 1)];
    const unsigned short* aptr = hb + (size_t)tokA * HDIM + kb * 8;
    f32x4 acc[4];
#pragma unroll
    for (int j = 0; j < 4; j++) acc[j] = (f32x4){0.f,0.f,0.f,0.f};
    for (int k0 = 0; k0 < HDIM; k0 += 32) {
      bf16x8 av = *(const bf16x8*)(aptr + k0);
#pragma unroll
      for (int j = 0; j < 4; j++) {
        int dcol = cg * 64 + j * 16 + m;
        bf16x8 bv = *(const bf16x8*)(wbase + (size_t)dcol * HDIM + k0 + kb * 8);
        acc[j] = __builtin_amdgcn_mfma_f32_16x16x32_bf16(av, bv, acc[j], 0, 0, 0);
      }
    }
    float bias[4];
#pragma unroll
    for (int j = 0; j < 4; j++) bias[j] = b2[e * DDIM + dq * 256 + cg * 64 + j * 16 + m];
#pragma unroll
    for (int r = 0; r < 4; r++) {
      int crow = rg * 16 + kb * 4 + r;
      if (crow < nrow) {
        int tok = order[ts + crow];
#pragma unroll
        for (int j = 0; j < 4; j++) {
          float v = acc[j][r] + bias[j];
          v = v > 0.f ? v : 0.f;
          out[(size_t)tok * DDIM + dq * 256 + cg * 64 + j * 16 + m] = v;
        }
      }
    }
  }
}

// ---------------- launch ----------------

extern "C" void kernel_launch(void* const* d_in, const int* in_sizes, int n_in,
                              void* d_out, int out_size, void* d_ws, size_t ws_size,
                              hipStream_t stream) {
  const float* x  = (const float*)d_in[0];
  const float* rw = (const float*)d_in[1];
  const float* rb = (const float*)d_in[2];
  const float* w1 = (const float*)d_in[3];
  const float* b1 = (const float*)d_in[4];
  const float* w2 = (const float*)d_in[5];
  const float* b2 = (const float*)d_in[6];
  float* out = (float*)d_out;

  char* ws = (char*)d_ws;
  unsigned short* xb   = (unsigned short*)(ws + 0);          //  8,388,608  x bf16 [N][D]
  unsigned short* w1t  = (unsigned short*)(ws + 8388608);    // 16,777,216  W1^T bf16 [E][H][D]
  unsigned short* w2t  = (unsigned short*)(ws + 25165824);   // 16,777,216  W2^T bf16 [E][D][H]
  unsigned short* hb   = (unsigned short*)(ws + 41943040);   //  2,097,152  h bf16 [N][H]
  unsigned short* rwhi = (unsigned short*)(ws + 44040192);   //     65,536
  unsigned short* rwlo = (unsigned short*)(ws + 44105728);   //     65,536
  int* routed  = (int*)(ws + 44171264);                      //     16,384
  int* order   = (int*)(ws + 44187648);                      //     16,384
  int* counts  = (int*)(ws + 44204032);                      //        128
  int* offsets = (int*)(ws + 44204160);                      //        256 (33 ints)
  int* cursors = (int*)(ws + 44204416);                      //        128

  init_counts_kernel<<<dim3(1), dim3(64), 0, stream>>>(counts);
  rw_cvt_kernel<<<dim3(128), dim3(256), 0, stream>>>(rw, rwhi, rwlo);
  transpose_cvt_kernel<<<dim3(16, 4, 32), dim3(256), 0, stream>>>(w1, w1t, 1024, 256);
  transpose_cvt_kernel<<<dim3(4, 16, 32), dim3(256), 0, stream>>>(w2, w2t, 256, 1024);
  router_kernel<<<dim3(256), dim3(64), 0, stream>>>(x, rwhi, rwlo, rb, xb, routed, counts);
  scan_kernel<<<dim3(1), dim3(64), 0, stream>>>(counts, offsets, cursors);
  scatter_kernel<<<dim3(16), dim3(256), 0, stream>>>(routed, cursors, order);
  expert_l1_kernel<<<dim3(32, 8), dim3(512), 0, stream>>>(xb, w1t, b1, offsets, order, hb);
  expert_l2_kernel<<<dim3(32, 8, 4), dim3(512), 0, stream>>>(hb, w2t, b2, offsets, order, out);
}

// Round 2
// 120.514 us; speedup vs baseline: 1.2401x; 1.2401x over previous
//
#include <hip/hip_runtime.h>

// MoE block: B=128,K=32 -> N=4096 tokens, D=1024, H=256, E=32, top-1 routing.
// out[tok] = relu(relu(x[tok] @ W1[e] + b1[e]) @ W2[e] + b2[e]), e = argmax(x@rw.T+rb)

#define N_TOK 4096
#define DDIM  1024
#define HDIM  256
#define NEXP  32

typedef __attribute__((ext_vector_type(8))) short bf16x8;   // 8 bf16 in 4 VGPRs
typedef __attribute__((ext_vector_type(4))) float f32x4;

__device__ __forceinline__ unsigned short f2bf(float f) {   // RNE f32->bf16
  union { float f; unsigned u; } v; v.f = f;
  unsigned r = v.u + 0x7FFFu + ((v.u >> 16) & 1u);
  return (unsigned short)(r >> 16);
}
__device__ __forceinline__ float bf2f(unsigned short h) {
  union { unsigned u; float f; } v; v.u = ((unsigned)h) << 16;
  return v.f;
}

// ---------------- prep: rw hi/lo split + counts init (one launch) ----------------

__global__ __launch_bounds__(256) void prep_kernel(const float* __restrict__ rw,
    unsigned short* __restrict__ rwhi, unsigned short* __restrict__ rwlo,
    int* __restrict__ counts) {
  if (blockIdx.x == 0 && threadIdx.x < NEXP) counts[threadIdx.x] = 0;
  int i = blockIdx.x * 256 + threadIdx.x;   // 32*1024 elements, grid=128
  float w = rw[i];
  unsigned short h = f2bf(w);
  rwhi[i] = h;
  rwlo[i] = f2bf(w - bf2f(h));
}

// ---------------- transpose + cvt, both weight tensors in one launch ----------------
// W1 [E][1024][256] f32 -> w1t [E][256][1024] bf16 ; W2 [E][256][1024] -> w2t [E][1024][256]
__global__ __launch_bounds__(256) void transpose_cvt2_kernel(
    const float* __restrict__ w1, const float* __restrict__ w2,
    unsigned short* __restrict__ w1t, unsigned short* __restrict__ w2t) {
  __shared__ float tile[64][65];            // +1 pad: conflict-free transposed read
  int mat = blockIdx.y >> 5, e = blockIdx.y & 31;
  const float* src; unsigned short* dst; int R, C, cT;
  if (mat == 0) { src = w1; dst = w1t; R = 1024; C = 256;  cT = 4;  }
  else          { src = w2; dst = w2t; R = 256;  C = 1024; cT = 16; }
  int tl = blockIdx.x;                      // 64 tiles of 64x64 per matrix
  int r0 = (tl / cT) * 64, c0 = (tl % cT) * 64;
  const float* s = src + (size_t)e * R * C;
  unsigned short* d = dst + (size_t)e * R * C;
  int t = threadIdx.x;
  int cl = t & 63, rl = t >> 6;             // 64 lanes contiguous in C: coalesced
#pragma unroll
  for (int i = 0; i < 16; i++) {
    int r = i * 4 + rl;
    tile[r][cl] = s[(size_t)(r0 + r) * C + (c0 + cl)];
  }
  __syncthreads();
#pragma unroll
  for (int i = 0; i < 16; i++) {
    int c = i * 4 + rl;
    d[(size_t)(c0 + c) * R + (r0 + cl)] = f2bf(tile[cl][c]);  // banks (cl+c)%32: clean
  }
}

// ---------------- router: fp32-accurate logits via 4-term bf16 split MFMA ----------------
// 512 thr = 8 waves per 16-token tile; wave w owns K window [w*128, w*128+128).
// Partial 16x16 logit tiles (two expert halves) are elementwise-summed in LDS;
// wave 0 adds bias and does the cross-lane argmax (first-index tie-break = np.argmax).
// A frag: row=lane&15, k=(lane>>4)*8+i ; B frag: col=lane&15, same k.
// C/D: col=lane&15, row=(lane>>4)*4+reg  [verified layout]
__global__ __launch_bounds__(512) void router_kernel(
    const float* __restrict__ x, const unsigned short* __restrict__ rwhi,
    const unsigned short* __restrict__ rwlo, const float* __restrict__ rb,
    unsigned short* __restrict__ xb, int* __restrict__ routed, int* __restrict__ counts) {
  __shared__ float red[8][64][8];     // [wave][lane][acc0 r0..3, acc1 r0..3]
  int b = blockIdx.x;                 // token tile of 16
  int w = threadIdx.x >> 6;           // K-slice
  int l = threadIdx.x & 63;
  int m = l & 15, kb = l >> 4;
  int tok = b * 16 + m;
  int kbase = w * 128;
  const float* xrow = x + (size_t)tok * DDIM + kbase + kb * 8;
  unsigned short* xbrow = xb + (size_t)tok * DDIM + kbase + kb * 8;
  const unsigned short* w0hi = rwhi + (size_t)m * DDIM + kbase + kb * 8;
  const unsigned short* w0lo = rwlo + (size_t)m * DDIM + kbase + kb * 8;
  const unsigned short* w1hi = rwhi + (size_t)(16 + m) * DDIM + kbase + kb * 8;
  const unsigned short* w1lo = rwlo + (size_t)(16 + m) * DDIM + kbase + kb * 8;
  f32x4 acc0 = {0.f,0.f,0.f,0.f}, acc1 = {0.f,0.f,0.f,0.f};
#pragma unroll
  for (int k0 = 0; k0 < 128; k0 += 32) {
    float4 xa = *(const float4*)(xrow + k0);
    float4 xc = *(const float4*)(xrow + k0 + 4);
    float xv[8] = {xa.x, xa.y, xa.z, xa.w, xc.x, xc.y, xc.z, xc.w};
    bf16x8 xhi, xlo;
#pragma unroll
    for (int i = 0; i < 8; i++) {
      unsigned short h = f2bf(xv[i]);
      xhi[i] = (short)h;
      xlo[i] = (short)f2bf(xv[i] - bf2f(h));
    }
    *(bf16x8*)(xbrow + k0) = xhi;     // xb written exactly once per (tok,k)
    bf16x8 wh0 = *(const bf16x8*)(w0hi + k0);
    bf16x8 wl0 = *(const bf16x8*)(w0lo + k0);
    bf16x8 wh1 = *(const bf16x8*)(w1hi + k0);
    bf16x8 wl1 = *(const bf16x8*)(w1lo + k0);
    acc0 = __builtin_amdgcn_mfma_f32_16x16x32_bf16(xhi, wh0, acc0, 0, 0, 0);
    acc0 = __builtin_amdgcn_mfma_f32_16x16x32_bf16(xlo, wh0, acc0, 0, 0, 0);
    acc0 = __builtin_amdgcn_mfma_f32_16x16x32_bf16(xhi, wl0, acc0, 0, 0, 0);
    acc0 = __builtin_amdgcn_mfma_f32_16x16x32_bf16(xlo, wl0, acc0, 0, 0, 0);
    acc1 = __builtin_amdgcn_mfma_f32_16x16x32_bf16(xhi, wh1, acc1, 0, 0, 0);
    acc1 = __builtin_amdgcn_mfma_f32_16x16x32_bf16(xlo, wh1, acc1, 0, 0, 0);
    acc1 = __builtin_amdgcn_mfma_f32_16x16x32_bf16(xhi, wl1, acc1, 0, 0, 0);
    acc1 = __builtin_amdgcn_mfma_f32_16x16x32_bf16(xlo, wl1, acc1, 0, 0, 0);
  }
  *(f32x4*)&red[w][l][0] = acc0;
  *(f32x4*)&red[w][l][4] = acc1;
  __syncthreads();
  if (w == 0) {
    f32x4 s0 = {0.f,0.f,0.f,0.f}, s1 = {0.f,0.f,0.f,0.f};
#pragma unroll
    for (int ww = 0; ww < 8; ww++) {
      s0 += *(const f32x4*)&red[ww][l][0];
      s1 += *(const f32x4*)&red[ww][l][4];
    }
    float rb0 = rb[m], rb1 = rb[16 + m];
#pragma unroll
    for (int r = 0; r < 4; r++) {     // token row = kb*4+r
      float v0 = s0[r] + rb0;
      float v1 = s1[r] + rb1;
      float val = v0; int idx = m;
      if (v1 > v0) { val = v1; idx = 16 + m; }   // ties -> smaller e (np.argmax)
#pragma unroll
      for (int s = 1; s < 16; s <<= 1) {
        float ov = __shfl_xor(val, s);
        int oi = __shfl_xor(idx, s);
        if (ov > val || (ov == val && oi < idx)) { val = ov; idx = oi; }
      }
      if (m == 0) {
        routed[b * 16 + kb * 4 + r] = idx;
        atomicAdd(&counts[idx], 1);
      }
    }
  }
}

// ---------------- scan + scatter in one single-block launch ----------------

__global__ __launch_bounds__(512) void scan_scatter_kernel(const int* __restrict__ counts,
    const int* __restrict__ routed, int* __restrict__ offsets, int* __restrict__ order) {
  __shared__ int soff[NEXP];
  int t = threadIdx.x;
  if (t == 0) {
    int acc = 0;
    for (int e = 0; e < NEXP; e++) { offsets[e] = acc; soff[e] = acc; acc += counts[e]; }
    offsets[NEXP] = acc;
  }
  __syncthreads();
  for (int n = t; n < N_TOK; n += 512) {
    int e = routed[n];
    int pos = atomicAdd(&soff[e], 1);  // intra-expert order arbitrary: output invariant
    order[pos] = n;
  }
}

// ---------------- grouped expert GEMMs ----------------
// L1: h[tok][0:256] = relu(xb[tok] @ W1[e] + b1[e]),  K=1024
// block: 512 thr = 8 waves; 32-token tile x 256 cols; wave = 16 rows x 64 cols (4 MFMA tiles)
__global__ __launch_bounds__(512) void expert_l1_kernel(
    const unsigned short* __restrict__ xb, const unsigned short* __restrict__ w1t,
    const float* __restrict__ b1, const int* __restrict__ offsets,
    const int* __restrict__ order, unsigned short* __restrict__ hb) {
  int e = blockIdx.x;
  int beg = offsets[e], end = offsets[e + 1];
  int ne = end - beg;
  if (ne <= 0) return;
  int w = threadIdx.x >> 6, l = threadIdx.x & 63;
  int rg = w >> 2, cg = w & 3;
  int m = l & 15, kb = l >> 4;
  const unsigned short* wbase = w1t + (size_t)e * HDIM * DDIM;
  int ntiles = (ne + 31) >> 5;
  for (int tile = blockIdx.y; tile < ntiles; tile += gridDim.y) {
    int ts = beg + tile * 32;
    int nrow = end - ts; if (nrow > 32) nrow = 32;
    int arow = rg * 16 + m;
    int tokA = order[ts + (arow < nrow ? arow : nrow - 1)];  // clamp: masked at store
    const unsigned short* aptr = xb + (size_t)tokA * DDIM + kb * 8;
    f32x4 acc[4];
#pragma unroll
    for (int j = 0; j < 4; j++) acc[j] = (f32x4){0.f,0.f,0.f,0.f};
    for (int k0 = 0; k0 < DDIM; k0 += 32) {
      bf16x8 av = *(const bf16x8*)(aptr + k0);
#pragma unroll
      for (int j = 0; j < 4; j++) {
        int col = cg * 64 + j * 16 + m;
        bf16x8 bv = *(const bf16x8*)(wbase + (size_t)col * DDIM + k0 + kb * 8);
        acc[j] = __builtin_amdgcn_mfma_f32_16x16x32_bf16(av, bv, acc[j], 0, 0, 0);
      }
    }
    float bias[4];
#pragma unroll
    for (int j = 0; j < 4; j++) bias[j] = b1[e * HDIM + cg * 64 + j * 16 + m];
#pragma unroll
    for (int r = 0; r < 4; r++) {
      int crow = rg * 16 + kb * 4 + r;
      if (crow < nrow) {
        int tok = order[ts + crow];
#pragma unroll
        for (int j = 0; j < 4; j++) {
          float v = acc[j][r] + bias[j];
          v = v > 0.f ? v : 0.f;
          hb[(size_t)tok * HDIM + cg * 64 + j * 16 + m] = f2bf(v);
        }
      }
    }
  }
}

// L2: out[tok][dq*256 : +256] = relu(hb[tok] @ W2[e] + b2[e]),  K=256
__global__ __launch_bounds__(512) void expert_l2_kernel(
    const unsigned short* __restrict__ hb, const unsigned short* __restrict__ w2t,
    const float* __restrict__ b2, const int* __restrict__ offsets,
    const int* __restrict__ order, float* __restrict__ out) {
  int e = blockIdx.x;
  int beg = offsets[e], end = offsets[e + 1];
  int ne = end - beg;
  if (ne <= 0) return;
  int w = threadIdx.x >> 6, l = threadIdx.x & 63;
  int rg = w >> 2, cg = w & 3;
  int m = l & 15, kb = l >> 4;
  int dq = blockIdx.z;                 // D quarter: 256 cols
  const unsigned short* wbase = w2t + (size_t)e * DDIM * HDIM + (size_t)dq * 256 * HDIM;
  int ntiles = (ne + 31) >> 5;
  for (int tile = blockIdx.y; tile < ntiles; tile += gridDim.y) {
    int ts = beg + tile * 32;
    int nrow = end - ts; if (nrow > 32) nrow = 32;
    int arow = rg * 16 + m;
    int tokA = order[ts + (arow < nrow ? arow : nrow - 1)];
    const unsigned short* aptr = hb + (size_t)tokA * HDIM + kb * 8;
    f32x4 acc[4];
#pragma unroll
    for (int j = 0; j < 4; j++) acc[j] = (f32x4){0.f,0.f,0.f,0.f};
    for (int k0 = 0; k0 < HDIM; k0 += 32) {
      bf16x8 av = *(const bf16x8*)(aptr + k0);
#pragma unroll
      for (int j = 0; j < 4; j++) {
        int dcol = cg * 64 + j * 16 + m;
        bf16x8 bv = *(const bf16x8*)(wbase + (size_t)dcol * HDIM + k0 + kb * 8);
        acc[j] = __builtin_amdgcn_mfma_f32_16x16x32_bf16(av, bv, acc[j], 0, 0, 0);
      }
    }
    float bias[4];
#pragma unroll
    for (int j = 0; j < 4; j++) bias[j] = b2[e * DDIM + dq * 256 + cg * 64 + j * 16 + m];
#pragma unroll
    for (int r = 0; r < 4; r++) {
      int crow = rg * 16 + kb * 4 + r;
      if (crow < nrow) {
        int tok = order[ts + crow];
#pragma unroll
        for (int j = 0; j < 4; j++) {
          float v = acc[j][r] + bias[j];
          v = v > 0.f ? v : 0.f;
          out[(size_t)tok * DDIM + dq * 256 + cg * 64 + j * 16 + m] = v;
        }
      }
    }
  }
}

// ---------------- launch ----------------

extern "C" void kernel_launch(void* const* d_in, const int* in_sizes, int n_in,
                              void* d_out, int out_size, void* d_ws, size_t ws_size,
                              hipStream_t stream) {
  const float* x  = (const float*)d_in[0];
  const float* rw = (const float*)d_in[1];
  const float* rb = (const float*)d_in[2];
  const float* w1 = (const float*)d_in[3];
  const float* b1 = (const float*)d_in[4];
  const float* w2 = (const float*)d_in[5];
  const float* b2 = (const float*)d_in[6];
  float* out = (float*)d_out;

  char* ws = (char*)d_ws;
  unsigned short* xb   = (unsigned short*)(ws + 0);          //  8,388,608  x bf16 [N][D]
  unsigned short* w1t  = (unsigned short*)(ws + 8388608);    // 16,777,216  W1^T bf16 [E][H][D]
  unsigned short* w2t  = (unsigned short*)(ws + 25165824);   // 16,777,216  W2^T bf16 [E][D][H]
  unsigned short* hb   = (unsigned short*)(ws + 41943040);   //  2,097,152  h bf16 [N][H]
  unsigned short* rwhi = (unsigned short*)(ws + 44040192);   //     65,536
  unsigned short* rwlo = (unsigned short*)(ws + 44105728);   //     65,536
  int* routed  = (int*)(ws + 44171264);                      //     16,384
  int* order   = (int*)(ws + 44187648);                      //     16,384
  int* counts  = (int*)(ws + 44204032);                      //        128
  int* offsets = (int*)(ws + 44204160);                      //        256 (33 ints)

  prep_kernel<<<dim3(128), dim3(256), 0, stream>>>(rw, rwhi, rwlo, counts);
  transpose_cvt2_kernel<<<dim3(64, 64), dim3(256), 0, stream>>>(w1, w2, w1t, w2t);
  router_kernel<<<dim3(256), dim3(512), 0, stream>>>(x, rwhi, rwlo, rb, xb, routed, counts);
  scan_scatter_kernel<<<dim3(1), dim3(512), 0, stream>>>(counts, routed, offsets, order);
  expert_l1_kernel<<<dim3(32, 8), dim3(512), 0, stream>>>(xb, w1t, b1, offsets, order, hb);
  expert_l2_kernel<<<dim3(32, 8, 4), dim3(512), 0, stream>>>(hb, w2t, b2, offsets, order, out);
}

// Round 3
// 89.437 us; speedup vs baseline: 1.6710x; 1.3475x over previous
//
#include <hip/hip_runtime.h>
#include <stdint.h>

// MoE block: B=128,K=32 -> N=4096 tokens, D=1024, H=256, E=32, top-1 routing.
// out[tok] = relu(relu(x[tok] @ W1[e] + b1[e]) @ W2[e] + b2[e]), e = argmax(x@rw.T+rb)

#define N_TOK 4096
#define DDIM  1024
#define HDIM  256
#define NEXP  32
#define MAXTILE 160   // >= max Sum_e ceil(ne/32) = 128+31

typedef __attribute__((ext_vector_type(8))) short bf16x8;   // 8 bf16 in 4 VGPRs
typedef __attribute__((ext_vector_type(4))) float f32x4;

__device__ __forceinline__ unsigned short f2bf(float f) {   // RNE f32->bf16
  union { float f; unsigned u; } v; v.f = f;
  unsigned r = v.u + 0x7FFFu + ((v.u >> 16) & 1u);
  return (unsigned short)(r >> 16);
}
__device__ __forceinline__ float bf2f(unsigned short h) {
  union { unsigned u; float f; } v; v.u = ((unsigned)h) << 16;
  return v.f;
}

// ---------------- prep: rw hi/lo split + counts init (one launch) ----------------

__global__ __launch_bounds__(256) void prep_kernel(const float* __restrict__ rw,
    unsigned short* __restrict__ rwhi, unsigned short* __restrict__ rwlo,
    int* __restrict__ counts) {
  if (blockIdx.x == 0 && threadIdx.x < NEXP) counts[threadIdx.x] = 0;
  int i = blockIdx.x * 256 + threadIdx.x;   // 32*1024 elements, grid=128
  float w = rw[i];
  unsigned short h = f2bf(w);
  rwhi[i] = h;
  rwlo[i] = f2bf(w - bf2f(h));
}

// ---------------- transpose + cvt, both weight tensors in one launch ----------------
// W1 [E][1024][256] f32 -> w1t [E][256][1024] bf16 ; W2 [E][256][1024] -> w2t [E][1024][256]
__global__ __launch_bounds__(256) void transpose_cvt2_kernel(
    const float* __restrict__ w1, const float* __restrict__ w2,
    unsigned short* __restrict__ w1t, unsigned short* __restrict__ w2t) {
  __shared__ float tile[64][65];            // +1 pad: conflict-free transposed read
  int mat = blockIdx.y >> 5, e = blockIdx.y & 31;
  const float* src; unsigned short* dst; int R, C, cT;
  if (mat == 0) { src = w1; dst = w1t; R = 1024; C = 256;  cT = 4;  }
  else          { src = w2; dst = w2t; R = 256;  C = 1024; cT = 16; }
  int tl = blockIdx.x;                      // 64 tiles of 64x64 per matrix
  int r0 = (tl / cT) * 64, c0 = (tl % cT) * 64;
  const float* s = src + (size_t)e * R * C;
  unsigned short* d = dst + (size_t)e * R * C;
  int t = threadIdx.x;
  int cl = t & 63, rl = t >> 6;             // 64 lanes contiguous in C: coalesced
#pragma unroll
  for (int i = 0; i < 16; i++) {
    int r = i * 4 + rl;
    tile[r][cl] = s[(size_t)(r0 + r) * C + (c0 + cl)];
  }
  __syncthreads();
#pragma unroll
  for (int i = 0; i < 16; i++) {
    int c = i * 4 + rl;
    d[(size_t)(c0 + c) * R + (r0 + cl)] = f2bf(tile[cl][c]);  // banks (cl+c)%32: clean
  }
}

// ---------------- router: fp32-accurate logits via 4-term bf16 split MFMA ----------------
// 512 thr = 8 waves per 16-token tile; wave w owns K window [w*128, w*128+128).
__global__ __launch_bounds__(512) void router_kernel(
    const float* __restrict__ x, const unsigned short* __restrict__ rwhi,
    const unsigned short* __restrict__ rwlo, const float* __restrict__ rb,
    unsigned short* __restrict__ xb, int* __restrict__ routed, int* __restrict__ counts) {
  __shared__ float red[8][64][8];     // [wave][lane][acc0 r0..3, acc1 r0..3]
  int b = blockIdx.x;                 // token tile of 16
  int w = threadIdx.x >> 6;           // K-slice
  int l = threadIdx.x & 63;
  int m = l & 15, kb = l >> 4;
  int tok = b * 16 + m;
  int kbase = w * 128;
  const float* xrow = x + (size_t)tok * DDIM + kbase + kb * 8;
  unsigned short* xbrow = xb + (size_t)tok * DDIM + kbase + kb * 8;
  const unsigned short* w0hi = rwhi + (size_t)m * DDIM + kbase + kb * 8;
  const unsigned short* w0lo = rwlo + (size_t)m * DDIM + kbase + kb * 8;
  const unsigned short* w1hi = rwhi + (size_t)(16 + m) * DDIM + kbase + kb * 8;
  const unsigned short* w1lo = rwlo + (size_t)(16 + m) * DDIM + kbase + kb * 8;
  f32x4 acc0 = {0.f,0.f,0.f,0.f}, acc1 = {0.f,0.f,0.f,0.f};
#pragma unroll
  for (int k0 = 0; k0 < 128; k0 += 32) {
    float4 xa = *(const float4*)(xrow + k0);
    float4 xc = *(const float4*)(xrow + k0 + 4);
    float xv[8] = {xa.x, xa.y, xa.z, xa.w, xc.x, xc.y, xc.z, xc.w};
    bf16x8 xhi, xlo;
#pragma unroll
    for (int i = 0; i < 8; i++) {
      unsigned short h = f2bf(xv[i]);
      xhi[i] = (short)h;
      xlo[i] = (short)f2bf(xv[i] - bf2f(h));
    }
    *(bf16x8*)(xbrow + k0) = xhi;     // xb written exactly once per (tok,k)
    bf16x8 wh0 = *(const bf16x8*)(w0hi + k0);
    bf16x8 wl0 = *(const bf16x8*)(w0lo + k0);
    bf16x8 wh1 = *(const bf16x8*)(w1hi + k0);
    bf16x8 wl1 = *(const bf16x8*)(w1lo + k0);
    acc0 = __builtin_amdgcn_mfma_f32_16x16x32_bf16(xhi, wh0, acc0, 0, 0, 0);
    acc0 = __builtin_amdgcn_mfma_f32_16x16x32_bf16(xlo, wh0, acc0, 0, 0, 0);
    acc0 = __builtin_amdgcn_mfma_f32_16x16x32_bf16(xhi, wl0, acc0, 0, 0, 0);
    acc0 = __builtin_amdgcn_mfma_f32_16x16x32_bf16(xlo, wl0, acc0, 0, 0, 0);
    acc1 = __builtin_amdgcn_mfma_f32_16x16x32_bf16(xhi, wh1, acc1, 0, 0, 0);
    acc1 = __builtin_amdgcn_mfma_f32_16x16x32_bf16(xlo, wh1, acc1, 0, 0, 0);
    acc1 = __builtin_amdgcn_mfma_f32_16x16x32_bf16(xhi, wl1, acc1, 0, 0, 0);
    acc1 = __builtin_amdgcn_mfma_f32_16x16x32_bf16(xlo, wl1, acc1, 0, 0, 0);
  }
  *(f32x4*)&red[w][l][0] = acc0;
  *(f32x4*)&red[w][l][4] = acc1;
  __syncthreads();
  if (w == 0) {
    f32x4 s0 = {0.f,0.f,0.f,0.f}, s1 = {0.f,0.f,0.f,0.f};
#pragma unroll
    for (int ww = 0; ww < 8; ww++) {
      s0 += *(const f32x4*)&red[ww][l][0];
      s1 += *(const f32x4*)&red[ww][l][4];
    }
    float rb0 = rb[m], rb1 = rb[16 + m];
#pragma unroll
    for (int r = 0; r < 4; r++) {     // token row = kb*4+r
      float v0 = s0[r] + rb0;
      float v1 = s1[r] + rb1;
      float val = v0; int idx = m;
      if (v1 > v0) { val = v1; idx = 16 + m; }   // ties -> smaller e (np.argmax)
#pragma unroll
      for (int s = 1; s < 16; s <<= 1) {
        float ov = __shfl_xor(val, s);
        int oi = __shfl_xor(idx, s);
        if (ov > val || (ov == val && oi < idx)) { val = ov; idx = oi; }
      }
      if (m == 0) {
        routed[b * 16 + kb * 4 + r] = idx;
        atomicAdd(&counts[idx], 1);
      }
    }
  }
}

// ---------------- scan + tile-list build + scatter (one single-block launch) ----------------
// tiles[i] = (e<<24) | (nrow<<16) | start_in_order ; meta[0] = n_tiles

__global__ __launch_bounds__(512) void scan_scatter_kernel(const int* __restrict__ counts,
    const int* __restrict__ routed, int* __restrict__ tiles, int* __restrict__ meta,
    int* __restrict__ order) {
  __shared__ int soff[NEXP];
  int t = threadIdx.x;
  if (t == 0) {
    int acc = 0, nt = 0;
    for (int e = 0; e < NEXP; e++) {
      soff[e] = acc;
      int c = counts[e];
      for (int s = 0; s < c; s += 32) {
        int nr = c - s; if (nr > 32) nr = 32;
        tiles[nt++] = (e << 24) | (nr << 16) | (acc + s);
      }
      acc += c;
    }
    meta[0] = nt;
  }
  __syncthreads();
  for (int n = t; n < N_TOK; n += 512) {
    int e = routed[n];
    int pos = atomicAdd(&soff[e], 1);  // intra-expert order arbitrary: output invariant
    order[pos] = n;
  }
}

// ---------------- grouped expert GEMMs: LDS-staged, reg-prefetch pipelined ----------------
// Block 256 thr = 4 waves computes one 32-token x 128-col tile.
// LDS: A[32][64] bf16 (4KB) + B[128][64] bf16 (16KB), single-buffered (write gated
// by barrier), XOR-swizzled: data chunk c of row r lives at slot c^(r&7) (16B slots)
// -> b128 frag reads/writes hit the 8-lanes-per-bank-quad floor instead of 16-way.
// Pipeline per K-chunk: [lgkm0+bar] ds_write(cur regs) ; issue global loads(next)->regs ;
// [lgkm0+bar] ; ds_read frags + MFMA.  Raw s_barrier keeps next-chunk vmcnt in flight.

#define GEMM_BODY(KDIM, ASRC_T, A_ROWLEN, B_ROWLEN)                                     \
  int ti = blockIdx.x;                                                                  \
  if (ti >= meta[0]) return;                                                            \
  int info = tiles[ti];                                                                 \
  int e = info >> 24, nrow = (info >> 16) & 0xff, ts = info & 0xffff;                   \
  int n0 = blockIdx.y * 128;                                                            \
  int t = threadIdx.x, w = t >> 6, l = t & 63;                                          \
  int m = l & 15, kb = l >> 4;                                                          \
  int srow = t >> 3, sc = t & 7;                                                        \
  int sx = (sc ^ (srow & 7)) * 8;                                                       \
  int tokA = order[ts + (srow < nrow ? srow : nrow - 1)];

__global__ __launch_bounds__(256) void expert_l1_kernel(
    const unsigned short* __restrict__ xb, const unsigned short* __restrict__ w1t,
    const float* __restrict__ b1, const int* __restrict__ tiles,
    const int* __restrict__ meta, const int* __restrict__ order,
    unsigned short* __restrict__ hb) {
  __shared__ unsigned short Al[32 * 64];
  __shared__ unsigned short Bl[128 * 64];
  GEMM_BODY(DDIM, xb, DDIM, DDIM)
  const unsigned short* aSrc = xb + (size_t)tokA * DDIM + sc * 8;
  const unsigned short* bSrc = w1t + (size_t)e * (HDIM * DDIM) +
                               (size_t)(n0 + srow) * DDIM + sc * 8;
  bf16x8 na  = *(const bf16x8*)(aSrc);
  bf16x8 nb0 = *(const bf16x8*)(bSrc);
  bf16x8 nb1 = *(const bf16x8*)(bSrc + 32 * DDIM);
  bf16x8 nb2 = *(const bf16x8*)(bSrc + 64 * DDIM);
  bf16x8 nb3 = *(const bf16x8*)(bSrc + 96 * DDIM);
  f32x4 acc00 = {0.f,0.f,0.f,0.f}, acc01 = acc00, acc10 = acc00, acc11 = acc00;
  const int nk = DDIM / 64;
  for (int kc = 0; kc < nk; kc++) {
    if (kc) {
      asm volatile("s_waitcnt lgkmcnt(0)" ::: "memory");   // my frag reads retired
      asm volatile("s_barrier" ::: "memory");              // all waves done reading
    }
    bf16x8 ca = na, cb0 = nb0, cb1 = nb1, cb2 = nb2, cb3 = nb3;
    if (kc + 1 < nk) {
      int ko = (kc + 1) * 64;
      na  = *(const bf16x8*)(aSrc + ko);
      nb0 = *(const bf16x8*)(bSrc + ko);
      nb1 = *(const bf16x8*)(bSrc + 32 * DDIM + ko);
      nb2 = *(const bf16x8*)(bSrc + 64 * DDIM + ko);
      nb3 = *(const bf16x8*)(bSrc + 96 * DDIM + ko);
    }
    *(bf16x8*)&Al[srow * 64 + sx] = ca;                    // waits cur loads (counted)
    *(bf16x8*)&Bl[(srow      ) * 64 + sx] = cb0;
    *(bf16x8*)&Bl[(srow + 32) * 64 + sx] = cb1;
    *(bf16x8*)&Bl[(srow + 64) * 64 + sx] = cb2;
    *(bf16x8*)&Bl[(srow + 96) * 64 + sx] = cb3;
    asm volatile("s_waitcnt lgkmcnt(0)" ::: "memory");     // writes visible
    asm volatile("s_barrier" ::: "memory");                // next loads stay in flight
#pragma unroll
    for (int kk = 0; kk < 2; kk++) {
      int sl = ((kk * 4 + kb) ^ (m & 7)) * 8;
      bf16x8 a0 = *(const bf16x8*)&Al[m * 64 + sl];
      bf16x8 a1 = *(const bf16x8*)&Al[(16 + m) * 64 + sl];
      bf16x8 b0 = *(const bf16x8*)&Bl[(w * 32 + m) * 64 + sl];
      bf16x8 b1 = *(const bf16x8*)&Bl[(w * 32 + 16 + m) * 64 + sl];
      acc00 = __builtin_amdgcn_mfma_f32_16x16x32_bf16(a0, b0, acc00, 0, 0, 0);
      acc01 = __builtin_amdgcn_mfma_f32_16x16x32_bf16(a0, b1, acc01, 0, 0, 0);
      acc10 = __builtin_amdgcn_mfma_f32_16x16x32_bf16(a1, b0, acc10, 0, 0, 0);
      acc11 = __builtin_amdgcn_mfma_f32_16x16x32_bf16(a1, b1, acc11, 0, 0, 0);
    }
  }
  int c0 = n0 + w * 32 + m, c1 = c0 + 16;
  float bias0 = b1[e * HDIM + c0], bias1 = b1[e * HDIM + c1];
#pragma unroll
  for (int rf = 0; rf < 2; rf++) {
    f32x4 va = rf ? acc10 : acc00;
    f32x4 vb = rf ? acc11 : acc01;
#pragma unroll
    for (int r = 0; r < 4; r++) {
      int crow = rf * 16 + kb * 4 + r;
      if (crow < nrow) {
        int tok = order[ts + crow];
        float v0 = va[r] + bias0; v0 = v0 > 0.f ? v0 : 0.f;
        float v1 = vb[r] + bias1; v1 = v1 > 0.f ? v1 : 0.f;
        hb[(size_t)tok * HDIM + c0] = f2bf(v0);
        hb[(size_t)tok * HDIM + c1] = f2bf(v1);
      }
    }
  }
}

__global__ __launch_bounds__(256) void expert_l2_kernel(
    const unsigned short* __restrict__ hb, const unsigned short* __restrict__ w2t,
    const float* __restrict__ b2, const int* __restrict__ tiles,
    const int* __restrict__ meta, const int* __restrict__ order,
    float* __restrict__ out) {
  __shared__ unsigned short Al[32 * 64];
  __shared__ unsigned short Bl[128 * 64];
  GEMM_BODY(HDIM, hb, HDIM, HDIM)
  const unsigned short* aSrc = hb + (size_t)tokA * HDIM + sc * 8;
  const unsigned short* bSrc = w2t + (size_t)e * (DDIM * HDIM) +
                               (size_t)(n0 + srow) * HDIM + sc * 8;
  bf16x8 na  = *(const bf16x8*)(aSrc);
  bf16x8 nb0 = *(const bf16x8*)(bSrc);
  bf16x8 nb1 = *(const bf16x8*)(bSrc + 32 * HDIM);
  bf16x8 nb2 = *(const bf16x8*)(bSrc + 64 * HDIM);
  bf16x8 nb3 = *(const bf16x8*)(bSrc + 96 * HDIM);
  f32x4 acc00 = {0.f,0.f,0.f,0.f}, acc01 = acc00, acc10 = acc00, acc11 = acc00;
  const int nk = HDIM / 64;   // 4
  for (int kc = 0; kc < nk; kc++) {
    if (kc) {
      asm volatile("s_waitcnt lgkmcnt(0)" ::: "memory");
      asm volatile("s_barrier" ::: "memory");
    }
    bf16x8 ca = na, cb0 = nb0, cb1 = nb1, cb2 = nb2, cb3 = nb3;
    if (kc + 1 < nk) {
      int ko = (kc + 1) * 64;
      na  = *(const bf16x8*)(aSrc + ko);
      nb0 = *(const bf16x8*)(bSrc + ko);
      nb1 = *(const bf16x8*)(bSrc + 32 * HDIM + ko);
      nb2 = *(const bf16x8*)(bSrc + 64 * HDIM + ko);
      nb3 = *(const bf16x8*)(bSrc + 96 * HDIM + ko);
    }
    *(bf16x8*)&Al[srow * 64 + sx] = ca;
    *(bf16x8*)&Bl[(srow      ) * 64 + sx] = cb0;
    *(bf16x8*)&Bl[(srow + 32) * 64 + sx] = cb1;
    *(bf16x8*)&Bl[(srow + 64) * 64 + sx] = cb2;
    *(bf16x8*)&Bl[(srow + 96) * 64 + sx] = cb3;
    asm volatile("s_waitcnt lgkmcnt(0)" ::: "memory");
    asm volatile("s_barrier" ::: "memory");
#pragma unroll
    for (int kk = 0; kk < 2; kk++) {
      int sl = ((kk * 4 + kb) ^ (m & 7)) * 8;
      bf16x8 a0 = *(const bf16x8*)&Al[m * 64 + sl];
      bf16x8 a1 = *(const bf16x8*)&Al[(16 + m) * 64 + sl];
      bf16x8 b0 = *(const bf16x8*)&Bl[(w * 32 + m) * 64 + sl];
      bf16x8 b1 = *(const bf16x8*)&Bl[(w * 32 + 16 + m) * 64 + sl];
      acc00 = __builtin_amdgcn_mfma_f32_16x16x32_bf16(a0, b0, acc00, 0, 0, 0);
      acc01 = __builtin_amdgcn_mfma_f32_16x16x32_bf16(a0, b1, acc01, 0, 0, 0);
      acc10 = __builtin_amdgcn_mfma_f32_16x16x32_bf16(a1, b0, acc10, 0, 0, 0);
      acc11 = __builtin_amdgcn_mfma_f32_16x16x32_bf16(a1, b1, acc11, 0, 0, 0);
    }
  }
  int c0 = n0 + w * 32 + m, c1 = c0 + 16;
  float bias0 = b2[e * DDIM + c0], bias1 = b2[e * DDIM + c1];
#pragma unroll
  for (int rf = 0; rf < 2; rf++) {
    f32x4 va = rf ? acc10 : acc00;
    f32x4 vb = rf ? acc11 : acc01;
#pragma unroll
    for (int r = 0; r < 4; r++) {
      int crow = rf * 16 + kb * 4 + r;
      if (crow < nrow) {
        int tok = order[ts + crow];
        float v0 = va[r] + bias0; v0 = v0 > 0.f ? v0 : 0.f;
        float v1 = vb[r] + bias1; v1 = v1 > 0.f ? v1 : 0.f;
        out[(size_t)tok * DDIM + c0] = v0;
        out[(size_t)tok * DDIM + c1] = v1;
      }
    }
  }
}

// ---------------- launch ----------------

extern "C" void kernel_launch(void* const* d_in, const int* in_sizes, int n_in,
                              void* d_out, int out_size, void* d_ws, size_t ws_size,
                              hipStream_t stream) {
  const float* x  = (const float*)d_in[0];
  const float* rw = (const float*)d_in[1];
  const float* rb = (const float*)d_in[2];
  const float* w1 = (const float*)d_in[3];
  const float* b1 = (const float*)d_in[4];
  const float* w2 = (const float*)d_in[5];
  const float* b2 = (const float*)d_in[6];
  float* out = (float*)d_out;

  char* ws = (char*)d_ws;
  unsigned short* xb   = (unsigned short*)(ws + 0);          //  8,388,608  x bf16 [N][D]
  unsigned short* w1t  = (unsigned short*)(ws + 8388608);    // 16,777,216  W1^T bf16 [E][H][D]
  unsigned short* w2t  = (unsigned short*)(ws + 25165824);   // 16,777,216  W2^T bf16 [E][D][H]
  unsigned short* hb   = (unsigned short*)(ws + 41943040);   //  2,097,152  h bf16 [N][H]
  unsigned short* rwhi = (unsigned short*)(ws + 44040192);   //     65,536
  unsigned short* rwlo = (unsigned short*)(ws + 44105728);   //     65,536
  int* routed  = (int*)(ws + 44171264);                      //     16,384
  int* order   = (int*)(ws + 44187648);                      //     16,384
  int* counts  = (int*)(ws + 44204032);                      //        128
  int* tiles   = (int*)(ws + 44204160);                      //      1,024 (MAXTILE ints)
  int* meta    = (int*)(ws + 44205184);                      //         64

  prep_kernel<<<dim3(128), dim3(256), 0, stream>>>(rw, rwhi, rwlo, counts);
  transpose_cvt2_kernel<<<dim3(64, 64), dim3(256), 0, stream>>>(w1, w2, w1t, w2t);
  router_kernel<<<dim3(256), dim3(512), 0, stream>>>(x, rwhi, rwlo, rb, xb, routed, counts);
  scan_scatter_kernel<<<dim3(1), dim3(512), 0, stream>>>(counts, routed, tiles, meta, order);
  expert_l1_kernel<<<dim3(MAXTILE, 2), dim3(256), 0, stream>>>(xb, w1t, b1, tiles, meta, order, hb);
  expert_l2_kernel<<<dim3(MAXTILE, 8), dim3(256), 0, stream>>>(hb, w2t, b2, tiles, meta, order, out);
}